// Round 2
// baseline (308.621 us; speedup 1.0000x reference)
//
#include <hip/hip_runtime.h>
#include <math.h>

#define HDIM 2048
#define NMB  512

// workspace layout (floats)
#define WS_GATES 0          // gf, gw, add, erase
#define WS_FRF   4          // 512
#define WS_WRF   516        // 12800
#define WS_FWF   13316      // 512
#define WS_WWF   13828      // 12800
#define WS_MWF   26628      // 100
#define WS_MWW   26728      // 196
#define WS_FOC   26924      // 100
#define WS_WIDE  27024      // 36

// out layout (floats)
#define OUT_READ 0          // 2048
#define OUT_FRF  2048       // 512
#define OUT_WRF  2560       // 12800
#define OUT_FWF  15360      // 512
#define OUT_WWF  15872      // 12800
#define OUT_MT   28672      // 51200

#define NROWS (4 + 512 + 12800 + 512 + 12800 + 100 + 196)  // 26924
#define ROWS_PER_WAVE 4
#define NWAVES (NROWS / ROWS_PER_WAVE)                     // 6731 exactly

__global__ __launch_bounds__(256) void k1_gemv(
    const float* __restrict__ h,
    const float* __restrict__ w_fg, const float* __restrict__ b_fg,
    const float* __restrict__ w_wg, const float* __restrict__ b_wg,
    const float* __restrict__ w_ag, const float* __restrict__ b_ag,
    const float* __restrict__ w_eg, const float* __restrict__ b_eg,
    const float* __restrict__ w_hrf, const float* __restrict__ b_hrf,
    const float* __restrict__ w_hrw, const float* __restrict__ b_hrw,
    const float* __restrict__ w_hwf, const float* __restrict__ b_hwf,
    const float* __restrict__ w_hww, const float* __restrict__ b_hww,
    const float* __restrict__ w_hfc, const float* __restrict__ b_hfc,
    const float* __restrict__ w_hwc, const float* __restrict__ b_hwc,
    float* __restrict__ ws)
{
    const int wave = (blockIdx.x * blockDim.x + threadIdx.x) >> 6;
    const int lane = threadIdx.x & 63;
    if (wave >= NWAVES) return;

    const float4* h4 = (const float4*)h;
    // rotate k-order per wave to decorrelate HBM channel phase across waves
    const int rot = (wave & 7) << 6;   // in float4 units, multiple of 64

    const int base = wave * ROWS_PER_WAVE;

#pragma unroll
    for (int rr = 0; rr < ROWS_PER_WAVE; ++rr) {
        const int r = base + rr;

        const float* w;
        const float* bias;
        int bi, act, oi;
        float* outp;
        if (r < 4) {
            if (r == 0)      { w = w_fg; bias = b_fg; }
            else if (r == 1) { w = w_wg; bias = b_wg; }
            else if (r == 2) { w = w_ag; bias = b_ag; }
            else             { w = w_eg; bias = b_eg; }
            bi = 0; act = (r < 2) ? 0 : 1; outp = ws + WS_GATES; oi = r;
        } else if (r < 4 + 512) {
            int k = r - 4;      w = w_hrf + (size_t)k * HDIM; bias = b_hrf; bi = k; act = 1; outp = ws + WS_FRF; oi = k;
        } else if (r < 4 + 512 + 12800) {
            int k = r - 516;    w = w_hrw + (size_t)k * HDIM; bias = b_hrw; bi = k; act = 1; outp = ws + WS_WRF; oi = k;
        } else if (r < 4 + 512 + 12800 + 512) {
            int k = r - 13316;  w = w_hwf + (size_t)k * HDIM; bias = b_hwf; bi = k; act = 1; outp = ws + WS_FWF; oi = k;
        } else if (r < 4 + 512 + 12800 + 512 + 12800) {
            int k = r - 13828;  w = w_hww + (size_t)k * HDIM; bias = b_hww; bi = k; act = 1; outp = ws + WS_WWF; oi = k;
        } else if (r < 4 + 512 + 12800 + 512 + 12800 + 100) {
            int k = r - 26628;  w = w_hfc + (size_t)k * HDIM; bias = b_hfc; bi = k; act = 2; outp = ws + WS_MWF; oi = k;
        } else {
            int k = r - 26728;  w = w_hwc + (size_t)k * HDIM; bias = b_hwc; bi = k; act = 2; outp = ws + WS_MWW; oi = k;
        }

        const float4* w4 = (const float4*)w;
        float acc = 0.f;
#pragma unroll
        for (int s = 0; s < 8; ++s) {
            int idx = (((s << 6) + rot) & 511) + lane;   // rotated slot, same for w & h
            float4 a = w4[idx];
            float4 b = h4[idx];
            acc += a.x * b.x + a.y * b.y + a.z * b.z + a.w * b.w;
        }
#pragma unroll
        for (int off = 32; off > 0; off >>= 1) acc += __shfl_down(acc, off);

        if (lane == 0) {
            float x = acc + bias[bi];
            float y;
            if (act == 0) {            // gate: clamp(1.2*sigmoid(x)-0.1, 0, 1)
                float s = 1.f / (1.f + __expf(-x));
                y = fminf(fmaxf(1.2f * s - 0.1f, 0.f), 1.f);
            } else if (act == 1) {     // hardtanh01
                y = fminf(fmaxf(x, 0.f), 1.f);
            } else {                   // relu
                y = fmaxf(x, 0.f);
            }
            outp[oi] = y;
        }
    }
}

// block 0..103   : elementwise gate-mix -> outputs frf_t / wrf_t / fwf_t / wwf_t
// block 104      : focused (100 outputs, reduce over 512 channels)
// block 105..140 : wide conv (36 outputs, reduce over 12800 taps)
// block 141..340 : m_t (51200 outputs, 25-tap conv each)
__global__ __launch_bounds__(256) void k2_mix_conv(
    const float* __restrict__ frf, const float* __restrict__ wrf,
    const float* __restrict__ fwf, const float* __restrict__ wwf,
    const float* __restrict__ m,
    float* __restrict__ ws, float* __restrict__ out)
{
    const float gf = ws[WS_GATES + 0];
    const float gw = ws[WS_GATES + 1];
    const float addg = ws[WS_GATES + 2];
    const float erg  = ws[WS_GATES + 3];
    const int b = blockIdx.x;
    const int tid = threadIdx.x;

    if (b < 104) {
        int e = b * 256 + tid;
        if (e < 512) {
            out[OUT_FRF + e] = ws[WS_FRF + e] * gf + frf[e] * (1.f - gf);
        } else if (e < 13312) {
            int k = e - 512;
            out[OUT_WRF + k] = ws[WS_WRF + k] * gw + wrf[k] * (1.f - gw);
        } else if (e < 13824) {
            int k = e - 13312;
            out[OUT_FWF + k] = ws[WS_FWF + k] * gf + fwf[k] * (1.f - gf);
        } else if (e < 26624) {
            int k = e - 13824;
            out[OUT_WWF + k] = ws[WS_WWF + k] * gw + wwf[k] * (1.f - gw);
        }
    } else if (b == 104) {
        __shared__ float sfrf[512];
        for (int e = tid; e < 512; e += 256)
            sfrf[e] = ws[WS_FRF + e] * gf + frf[e] * (1.f - gf);
        __syncthreads();
        if (tid < 100) {
            float acc = 0.f;
            for (int c = 0; c < 512; ++c) acc += sfrf[c] * m[c * 100 + tid];
            ws[WS_FOC + tid] = fmaxf(acc, 0.f);
        }
    } else if (b < 141) {
        int o = b - 105;
        int i = o / 6, j = o % 6;
        float acc = 0.f;
        for (int k = tid; k < 12800; k += 256) {
            int c = k / 25, pq = k % 25, p = pq / 5, q = pq % 5;
            float wm = ws[WS_WRF + k] * gw + wrf[k] * (1.f - gw);
            acc += wm * m[c * 100 + (i + p) * 10 + (j + q)];
        }
        __shared__ float red[256];
        red[tid] = acc;
        __syncthreads();
        for (int s = 128; s > 0; s >>= 1) {
            if (tid < s) red[tid] += red[tid + s];
            __syncthreads();
        }
        if (tid == 0) ws[WS_WIDE + o] = fmaxf(red[0], 0.f);
    } else {
        __shared__ float smwf[100];
        __shared__ float smww[196];
        if (tid < 100) smwf[tid] = ws[WS_MWF + tid];
        if (tid < 196) smww[tid] = ws[WS_MWW + tid];
        __syncthreads();
        int t = (b - 141) * 256 + tid;   // < 51200
        int c = t / 100, hw = t % 100;
        int i = hw / 10, j = hw % 10;
        float fwf_t = ws[WS_FWF + c] * gf + fwf[c] * (1.f - gf);
        float wwacc = 0.f;
#pragma unroll
        for (int p = 0; p < 5; ++p) {
#pragma unroll
            for (int q = 0; q < 5; ++q) {
                int k = c * 25 + p * 5 + q;
                float wm = ws[WS_WWF + k] * gw + wwf[k] * (1.f - gw);
                wwacc += wm * smww[(i + p) * 14 + (j + q)];
            }
        }
        out[OUT_MT + t] = m[t] + (smwf[hw] * fwf_t + wwacc) * (1.f - erg) + 2.f * addg;
    }
}

__global__ __launch_bounds__(256) void k3_read(
    const float* __restrict__ w_cfr, const float* __restrict__ b_cfr,
    const float* __restrict__ w_cwr, const float* __restrict__ b_cwr,
    const float* __restrict__ ws, float* __restrict__ out)
{
    const int wave = (blockIdx.x * blockDim.x + threadIdx.x) >> 6;
    const int lane = threadIdx.x & 63;
    if (wave >= 2048) return;
    const float* foc = ws + WS_FOC;
    const float* wid = ws + WS_WIDE;

    float af = w_cfr[wave * 100 + lane] * foc[lane];     // lane in [0,64) < 100
    int k2 = lane + 64;
    if (k2 < 100) af += w_cfr[wave * 100 + k2] * foc[k2];
    float aw = (lane < 36) ? w_cwr[wave * 36 + lane] * wid[lane] : 0.f;
#pragma unroll
    for (int off = 32; off > 0; off >>= 1) {
        af += __shfl_down(af, off);
        aw += __shfl_down(aw, off);
    }
    if (lane == 0)
        out[wave] = (aw + b_cwr[wave]) + fmaxf(af + b_cfr[wave], 0.f);
}

extern "C" void kernel_launch(void* const* d_in, const int* in_sizes, int n_in,
                              void* d_out, int out_size, void* d_ws, size_t ws_size,
                              hipStream_t stream) {
    const float* h_t  = (const float*)d_in[0];
    const float* frf  = (const float*)d_in[1];
    const float* wrf  = (const float*)d_in[2];
    const float* fwf  = (const float*)d_in[3];
    const float* wwf  = (const float*)d_in[4];
    const float* m    = (const float*)d_in[5];
    const float* w_fg = (const float*)d_in[6];  const float* b_fg = (const float*)d_in[7];
    const float* w_wg = (const float*)d_in[8];  const float* b_wg = (const float*)d_in[9];
    const float* w_hrf= (const float*)d_in[10]; const float* b_hrf= (const float*)d_in[11];
    const float* w_hrw= (const float*)d_in[12]; const float* b_hrw= (const float*)d_in[13];
    const float* w_cfr= (const float*)d_in[14]; const float* b_cfr= (const float*)d_in[15];
    const float* w_cwr= (const float*)d_in[16]; const float* b_cwr= (const float*)d_in[17];
    const float* w_hfc= (const float*)d_in[18]; const float* b_hfc= (const float*)d_in[19];
    const float* w_hwc= (const float*)d_in[20]; const float* b_hwc= (const float*)d_in[21];
    const float* w_ag = (const float*)d_in[22]; const float* b_ag = (const float*)d_in[23];
    const float* w_eg = (const float*)d_in[24]; const float* b_eg = (const float*)d_in[25];
    const float* w_hwf= (const float*)d_in[26]; const float* b_hwf= (const float*)d_in[27];
    const float* w_hww= (const float*)d_in[28]; const float* b_hww= (const float*)d_in[29];

    float* out = (float*)d_out;
    float* ws  = (float*)d_ws;

    // K1: all h-projections (4 rows per wave, rotated k-order)
    {
        int blocks = (NWAVES * 64 + 255) / 256;
        hipLaunchKernelGGL(k1_gemv, dim3(blocks), dim3(256), 0, stream,
            h_t,
            w_fg, b_fg, w_wg, b_wg, w_ag, b_ag, w_eg, b_eg,
            w_hrf, b_hrf, w_hrw, b_hrw, w_hwf, b_hwf, w_hww, b_hww,
            w_hfc, b_hfc, w_hwc, b_hwc,
            ws);
    }
    // K2: gate-mix + convs + m_t
    hipLaunchKernelGGL(k2_mix_conv, dim3(341), dim3(256), 0, stream,
        frf, wrf, fwf, wwf, m, ws, out);
    // K3: read projection (one wave per row)
    hipLaunchKernelGGL(k3_read, dim3(512), dim3(256), 0, stream,
        w_cfr, b_cfr, w_cwr, b_cwr, ws, out);
}

// Round 3
// 305.253 us; speedup vs baseline: 1.0110x; 1.0110x over previous
//
#include <hip/hip_runtime.h>
#include <math.h>

#define HDIM 2048
#define NMB  512

// workspace layout (floats)
#define WS_GATES 0          // gf, gw, add, erase
#define WS_FRF   4          // 512
#define WS_WRF   516        // 12800
#define WS_FWF   13316      // 512
#define WS_WWF   13828      // 12800
#define WS_MWF   26628      // 100
#define WS_MWW   26728      // 196
#define WS_FOC   26924      // 100
#define WS_WIDE  27024      // 36

// out layout (floats)
#define OUT_READ 0          // 2048
#define OUT_FRF  2048       // 512
#define OUT_WRF  2560       // 12800
#define OUT_FWF  15360      // 512
#define OUT_WWF  15872      // 12800
#define OUT_MT   28672      // 51200

#define NROWS (4 + 512 + 12800 + 512 + 12800 + 100 + 196)  // 26924
#define NPAIRS (NROWS / 2)                                 // 13462

__global__ __launch_bounds__(256) void k1_gemv(
    const float* __restrict__ h,
    const float* __restrict__ w_fg, const float* __restrict__ b_fg,
    const float* __restrict__ w_wg, const float* __restrict__ b_wg,
    const float* __restrict__ w_ag, const float* __restrict__ b_ag,
    const float* __restrict__ w_eg, const float* __restrict__ b_eg,
    const float* __restrict__ w_hrf, const float* __restrict__ b_hrf,
    const float* __restrict__ w_hrw, const float* __restrict__ b_hrw,
    const float* __restrict__ w_hwf, const float* __restrict__ b_hwf,
    const float* __restrict__ w_hww, const float* __restrict__ b_hww,
    const float* __restrict__ w_hfc, const float* __restrict__ b_hfc,
    const float* __restrict__ w_hwc, const float* __restrict__ b_hwc,
    float* __restrict__ ws)
{
    const int lane = threadIdx.x & 63;
    const int wid  = (blockIdx.x * blockDim.x + threadIdx.x) >> 6;
    const int nw   = (gridDim.x * blockDim.x) >> 6;

    // h loaded ONCE per wave into registers (8 KB, L1-resident)
    const float4* h4 = (const float4*)h;
    float4 hv[8];
#pragma unroll
    for (int s = 0; s < 8; ++s) hv[s] = h4[(s << 6) + lane];

    for (int g = wid; g < NPAIRS; g += nw) {
        const int r0 = g * 2;

        const float* wp[2]; const float* bp[2];
        int bi[2], act[2], oi[2]; float* op[2];
#pragma unroll
        for (int t = 0; t < 2; ++t) {
            int r = r0 + t;
            if (r < 4) {
                if (r == 0)      { wp[t] = w_fg; bp[t] = b_fg; }
                else if (r == 1) { wp[t] = w_wg; bp[t] = b_wg; }
                else if (r == 2) { wp[t] = w_ag; bp[t] = b_ag; }
                else             { wp[t] = w_eg; bp[t] = b_eg; }
                bi[t] = 0; act[t] = (r < 2) ? 0 : 1; op[t] = ws + WS_GATES; oi[t] = r;
            } else if (r < 516) {
                int k = r - 4;      wp[t] = w_hrf + (size_t)k * HDIM; bp[t] = b_hrf; bi[t] = k; act[t] = 1; op[t] = ws + WS_FRF; oi[t] = k;
            } else if (r < 13316) {
                int k = r - 516;    wp[t] = w_hrw + (size_t)k * HDIM; bp[t] = b_hrw; bi[t] = k; act[t] = 1; op[t] = ws + WS_WRF; oi[t] = k;
            } else if (r < 13828) {
                int k = r - 13316;  wp[t] = w_hwf + (size_t)k * HDIM; bp[t] = b_hwf; bi[t] = k; act[t] = 1; op[t] = ws + WS_FWF; oi[t] = k;
            } else if (r < 26628) {
                int k = r - 13828;  wp[t] = w_hww + (size_t)k * HDIM; bp[t] = b_hww; bi[t] = k; act[t] = 1; op[t] = ws + WS_WWF; oi[t] = k;
            } else if (r < 26728) {
                int k = r - 26628;  wp[t] = w_hfc + (size_t)k * HDIM; bp[t] = b_hfc; bi[t] = k; act[t] = 2; op[t] = ws + WS_MWF; oi[t] = k;
            } else {
                int k = r - 26728;  wp[t] = w_hwc + (size_t)k * HDIM; bp[t] = b_hwc; bi[t] = k; act[t] = 2; op[t] = ws + WS_MWW; oi[t] = k;
            }
        }

        const float4* wA4 = (const float4*)wp[0];
        const float4* wB4 = (const float4*)wp[1];

        // issue all 16 weight loads back-to-back (affine: base + imm offsets)
        float4 av[8], bv[8];
#pragma unroll
        for (int s = 0; s < 8; ++s) av[s] = wA4[(s << 6) + lane];
#pragma unroll
        for (int s = 0; s < 8; ++s) bv[s] = wB4[(s << 6) + lane];

        float accA = 0.f, accB = 0.f;
#pragma unroll
        for (int s = 0; s < 8; ++s) {
            accA += av[s].x * hv[s].x + av[s].y * hv[s].y + av[s].z * hv[s].z + av[s].w * hv[s].w;
            accB += bv[s].x * hv[s].x + bv[s].y * hv[s].y + bv[s].z * hv[s].z + bv[s].w * hv[s].w;
        }
        // two independent butterfly reduce chains, interleaved
#pragma unroll
        for (int off = 32; off > 0; off >>= 1) {
            accA += __shfl_down(accA, off);
            accB += __shfl_down(accB, off);
        }

        if (lane == 0) {
#pragma unroll
            for (int t = 0; t < 2; ++t) {
                float x = ((t == 0) ? accA : accB) + bp[t][bi[t]];
                float y;
                if (act[t] == 0) {
                    float s = 1.f / (1.f + __expf(-x));
                    y = fminf(fmaxf(1.2f * s - 0.1f, 0.f), 1.f);
                } else if (act[t] == 1) {
                    y = fminf(fmaxf(x, 0.f), 1.f);
                } else {
                    y = fmaxf(x, 0.f);
                }
                op[t][oi[t]] = y;
            }
        }
    }
}

// block 0..103   : elementwise gate-mix -> outputs frf_t / wrf_t / fwf_t / wwf_t
// block 104      : focused (100 outputs, reduce over 512 channels)
// block 105..140 : wide conv (36 outputs, reduce over 12800 taps)
// block 141..340 : m_t (51200 outputs, 25-tap conv each)
__global__ __launch_bounds__(256) void k2_mix_conv(
    const float* __restrict__ frf, const float* __restrict__ wrf,
    const float* __restrict__ fwf, const float* __restrict__ wwf,
    const float* __restrict__ m,
    float* __restrict__ ws, float* __restrict__ out)
{
    const float gf = ws[WS_GATES + 0];
    const float gw = ws[WS_GATES + 1];
    const float addg = ws[WS_GATES + 2];
    const float erg  = ws[WS_GATES + 3];
    const int b = blockIdx.x;
    const int tid = threadIdx.x;

    if (b < 104) {
        int e = b * 256 + tid;
        if (e < 512) {
            out[OUT_FRF + e] = ws[WS_FRF + e] * gf + frf[e] * (1.f - gf);
        } else if (e < 13312) {
            int k = e - 512;
            out[OUT_WRF + k] = ws[WS_WRF + k] * gw + wrf[k] * (1.f - gw);
        } else if (e < 13824) {
            int k = e - 13312;
            out[OUT_FWF + k] = ws[WS_FWF + k] * gf + fwf[k] * (1.f - gf);
        } else if (e < 26624) {
            int k = e - 13824;
            out[OUT_WWF + k] = ws[WS_WWF + k] * gw + wwf[k] * (1.f - gw);
        }
    } else if (b == 104) {
        __shared__ float sfrf[512];
        for (int e = tid; e < 512; e += 256)
            sfrf[e] = ws[WS_FRF + e] * gf + frf[e] * (1.f - gf);
        __syncthreads();
        if (tid < 100) {
            float acc = 0.f;
            for (int c = 0; c < 512; ++c) acc += sfrf[c] * m[c * 100 + tid];
            ws[WS_FOC + tid] = fmaxf(acc, 0.f);
        }
    } else if (b < 141) {
        int o = b - 105;
        int i = o / 6, j = o % 6;
        float acc = 0.f;
        for (int k = tid; k < 12800; k += 256) {
            int c = k / 25, pq = k % 25, p = pq / 5, q = pq % 5;
            float wm = ws[WS_WRF + k] * gw + wrf[k] * (1.f - gw);
            acc += wm * m[c * 100 + (i + p) * 10 + (j + q)];
        }
        __shared__ float red[256];
        red[tid] = acc;
        __syncthreads();
        for (int s = 128; s > 0; s >>= 1) {
            if (tid < s) red[tid] += red[tid + s];
            __syncthreads();
        }
        if (tid == 0) ws[WS_WIDE + o] = fmaxf(red[0], 0.f);
    } else {
        __shared__ float smwf[100];
        __shared__ float smww[196];
        if (tid < 100) smwf[tid] = ws[WS_MWF + tid];
        if (tid < 196) smww[tid] = ws[WS_MWW + tid];
        __syncthreads();
        int t = (b - 141) * 256 + tid;   // < 51200
        int c = t / 100, hw = t % 100;
        int i = hw / 10, j = hw % 10;
        float fwf_t = ws[WS_FWF + c] * gf + fwf[c] * (1.f - gf);
        float wwacc = 0.f;
#pragma unroll
        for (int p = 0; p < 5; ++p) {
#pragma unroll
            for (int q = 0; q < 5; ++q) {
                int k = c * 25 + p * 5 + q;
                float wm = ws[WS_WWF + k] * gw + wwf[k] * (1.f - gw);
                wwacc += wm * smww[(i + p) * 14 + (j + q)];
            }
        }
        out[OUT_MT + t] = m[t] + (smwf[hw] * fwf_t + wwacc) * (1.f - erg) + 2.f * addg;
    }
}

__global__ __launch_bounds__(256) void k3_read(
    const float* __restrict__ w_cfr, const float* __restrict__ b_cfr,
    const float* __restrict__ w_cwr, const float* __restrict__ b_cwr,
    const float* __restrict__ ws, float* __restrict__ out)
{
    const int wave = (blockIdx.x * blockDim.x + threadIdx.x) >> 6;
    const int lane = threadIdx.x & 63;
    if (wave >= 2048) return;
    const float* foc = ws + WS_FOC;
    const float* wid = ws + WS_WIDE;

    float af = w_cfr[wave * 100 + lane] * foc[lane];     // lane in [0,64) < 100
    int k2 = lane + 64;
    if (k2 < 100) af += w_cfr[wave * 100 + k2] * foc[k2];
    float aw = (lane < 36) ? w_cwr[wave * 36 + lane] * wid[lane] : 0.f;
#pragma unroll
    for (int off = 32; off > 0; off >>= 1) {
        af += __shfl_down(af, off);
        aw += __shfl_down(aw, off);
    }
    if (lane == 0)
        out[wave] = (aw + b_cwr[wave]) + fmaxf(af + b_cfr[wave], 0.f);
}

extern "C" void kernel_launch(void* const* d_in, const int* in_sizes, int n_in,
                              void* d_out, int out_size, void* d_ws, size_t ws_size,
                              hipStream_t stream) {
    const float* h_t  = (const float*)d_in[0];
    const float* frf  = (const float*)d_in[1];
    const float* wrf  = (const float*)d_in[2];
    const float* fwf  = (const float*)d_in[3];
    const float* wwf  = (const float*)d_in[4];
    const float* m    = (const float*)d_in[5];
    const float* w_fg = (const float*)d_in[6];  const float* b_fg = (const float*)d_in[7];
    const float* w_wg = (const float*)d_in[8];  const float* b_wg = (const float*)d_in[9];
    const float* w_hrf= (const float*)d_in[10]; const float* b_hrf= (const float*)d_in[11];
    const float* w_hrw= (const float*)d_in[12]; const float* b_hrw= (const float*)d_in[13];
    const float* w_cfr= (const float*)d_in[14]; const float* b_cfr= (const float*)d_in[15];
    const float* w_cwr= (const float*)d_in[16]; const float* b_cwr= (const float*)d_in[17];
    const float* w_hfc= (const float*)d_in[18]; const float* b_hfc= (const float*)d_in[19];
    const float* w_hwc= (const float*)d_in[20]; const float* b_hwc= (const float*)d_in[21];
    const float* w_ag = (const float*)d_in[22]; const float* b_ag = (const float*)d_in[23];
    const float* w_eg = (const float*)d_in[24]; const float* b_eg = (const float*)d_in[25];
    const float* w_hwf= (const float*)d_in[26]; const float* b_hwf= (const float*)d_in[27];
    const float* w_hww= (const float*)d_in[28]; const float* b_hww= (const float*)d_in[29];

    float* out = (float*)d_out;
    float* ws  = (float*)d_ws;

    // K1: 2 rows per wave in flight, h hoisted to registers, 2 pairs per wave
    hipLaunchKernelGGL(k1_gemv, dim3(1683), dim3(256), 0, stream,
        h_t,
        w_fg, b_fg, w_wg, b_wg, w_ag, b_ag, w_eg, b_eg,
        w_hrf, b_hrf, w_hrw, b_hrw, w_hwf, b_hwf, w_hww, b_hww,
        w_hfc, b_hfc, w_hwc, b_hwc,
        ws);
    // K2: gate-mix + convs + m_t
    hipLaunchKernelGGL(k2_mix_conv, dim3(341), dim3(256), 0, stream,
        frf, wrf, fwf, wwf, m, ws, out);
    // K3: read projection (one wave per row)
    hipLaunchKernelGGL(k3_read, dim3(512), dim3(256), 0, stream,
        w_cfr, b_cfr, w_cwr, b_cwr, ws, out);
}

// Round 5
// 284.656 us; speedup vs baseline: 1.0842x; 1.0724x over previous
//
#include <hip/hip_runtime.h>
#include <math.h>

#define HDIM 2048
#define NMB  512

// workspace layout (floats)
#define WS_GATES 0          // gf, gw, add, erase
#define WS_FRF   4          // 512
#define WS_WRF   516        // 12800
#define WS_FWF   13316      // 512
#define WS_WWF   13828      // 12800
#define WS_MWF   26628      // 100
#define WS_MWW   26728      // 196
#define WS_FOC   26924      // 100
#define WS_WIDE  27024      // 36

// out layout (floats)
#define OUT_READ 0          // 2048
#define OUT_FRF  2048       // 512
#define OUT_WRF  2560       // 12800
#define OUT_FWF  15360      // 512
#define OUT_WWF  15872      // 12800
#define OUT_MT   28672      // 51200

#define NROWS (4 + 512 + 12800 + 512 + 12800 + 100 + 196)  // 26924
#define ROWS_PER_WAVE 4
#define NWAVES (NROWS / ROWS_PER_WAVE)                     // 6731 exactly

typedef float vfloat4 __attribute__((ext_vector_type(4)));

__global__ __launch_bounds__(256) void k1_gemv(
    const float* __restrict__ h,
    const float* __restrict__ w_fg, const float* __restrict__ b_fg,
    const float* __restrict__ w_wg, const float* __restrict__ b_wg,
    const float* __restrict__ w_ag, const float* __restrict__ b_ag,
    const float* __restrict__ w_eg, const float* __restrict__ b_eg,
    const float* __restrict__ w_hrf, const float* __restrict__ b_hrf,
    const float* __restrict__ w_hrw, const float* __restrict__ b_hrw,
    const float* __restrict__ w_hwf, const float* __restrict__ b_hwf,
    const float* __restrict__ w_hww, const float* __restrict__ b_hww,
    const float* __restrict__ w_hfc, const float* __restrict__ b_hfc,
    const float* __restrict__ w_hwc, const float* __restrict__ b_hwc,
    float* __restrict__ ws)
{
    const int wave = (blockIdx.x * blockDim.x + threadIdx.x) >> 6;
    const int lane = threadIdx.x & 63;
    if (wave >= NWAVES) return;

    // h loaded once per wave into registers (normal cached loads)
    const vfloat4* h4 = (const vfloat4*)h;
    vfloat4 hv[8];
#pragma unroll
    for (int s = 0; s < 8; ++s) hv[s] = h4[(s << 6) + lane];

    const int base = wave * ROWS_PER_WAVE;

    for (int rr = 0; rr < ROWS_PER_WAVE; ++rr) {
        const int r = base + rr;

        const float* w;
        const float* bias;
        int bi, act, oi;
        float* outp;
        if (r < 4) {
            if (r == 0)      { w = w_fg; bias = b_fg; }
            else if (r == 1) { w = w_wg; bias = b_wg; }
            else if (r == 2) { w = w_ag; bias = b_ag; }
            else             { w = w_eg; bias = b_eg; }
            bi = 0; act = (r < 2) ? 0 : 1; outp = ws + WS_GATES; oi = r;
        } else if (r < 516) {
            int k = r - 4;      w = w_hrf + (size_t)k * HDIM; bias = b_hrf; bi = k; act = 1; outp = ws + WS_FRF; oi = k;
        } else if (r < 13316) {
            int k = r - 516;    w = w_hrw + (size_t)k * HDIM; bias = b_hrw; bi = k; act = 1; outp = ws + WS_WRF; oi = k;
        } else if (r < 13828) {
            int k = r - 13316;  w = w_hwf + (size_t)k * HDIM; bias = b_hwf; bi = k; act = 1; outp = ws + WS_FWF; oi = k;
        } else if (r < 26628) {
            int k = r - 13828;  w = w_hww + (size_t)k * HDIM; bias = b_hww; bi = k; act = 1; outp = ws + WS_WWF; oi = k;
        } else if (r < 26728) {
            int k = r - 26628;  w = w_hfc + (size_t)k * HDIM; bias = b_hfc; bi = k; act = 2; outp = ws + WS_MWF; oi = k;
        } else {
            int k = r - 26728;  w = w_hwc + (size_t)k * HDIM; bias = b_hwc; bi = k; act = 2; outp = ws + WS_MWW; oi = k;
        }

        const vfloat4* w4 = (const vfloat4*)w;
        // nontemporal streaming loads for the weight row (bypass cache allocation)
        vfloat4 av[8];
#pragma unroll
        for (int s = 0; s < 8; ++s)
            av[s] = __builtin_nontemporal_load(&w4[(s << 6) + lane]);

        float acc = 0.f;
#pragma unroll
        for (int s = 0; s < 8; ++s)
            acc += av[s].x * hv[s].x + av[s].y * hv[s].y + av[s].z * hv[s].z + av[s].w * hv[s].w;

#pragma unroll
        for (int off = 32; off > 0; off >>= 1) acc += __shfl_down(acc, off);

        if (lane == 0) {
            float x = acc + bias[bi];
            float y;
            if (act == 0) {            // gate: clamp(1.2*sigmoid(x)-0.1, 0, 1)
                float s = 1.f / (1.f + __expf(-x));
                y = fminf(fmaxf(1.2f * s - 0.1f, 0.f), 1.f);
            } else if (act == 1) {     // hardtanh01
                y = fminf(fmaxf(x, 0.f), 1.f);
            } else {                   // relu
                y = fmaxf(x, 0.f);
            }
            outp[oi] = y;
        }
    }
}

// block 0..103   : elementwise gate-mix -> outputs frf_t / wrf_t / fwf_t / wwf_t
// block 104      : focused (100 outputs, reduce over 512 channels)
// block 105..140 : wide conv (36 outputs, reduce over 12800 taps)
// block 141..340 : m_t (51200 outputs, 25-tap conv each)
__global__ __launch_bounds__(256) void k2_mix_conv(
    const float* __restrict__ frf, const float* __restrict__ wrf,
    const float* __restrict__ fwf, const float* __restrict__ wwf,
    const float* __restrict__ m,
    float* __restrict__ ws, float* __restrict__ out)
{
    const float gf = ws[WS_GATES + 0];
    const float gw = ws[WS_GATES + 1];
    const float addg = ws[WS_GATES + 2];
    const float erg  = ws[WS_GATES + 3];
    const int b = blockIdx.x;
    const int tid = threadIdx.x;

    if (b < 104) {
        int e = b * 256 + tid;
        if (e < 512) {
            out[OUT_FRF + e] = ws[WS_FRF + e] * gf + frf[e] * (1.f - gf);
        } else if (e < 13312) {
            int k = e - 512;
            out[OUT_WRF + k] = ws[WS_WRF + k] * gw + wrf[k] * (1.f - gw);
        } else if (e < 13824) {
            int k = e - 13312;
            out[OUT_FWF + k] = ws[WS_FWF + k] * gf + fwf[k] * (1.f - gf);
        } else if (e < 26624) {
            int k = e - 13824;
            out[OUT_WWF + k] = ws[WS_WWF + k] * gw + wwf[k] * (1.f - gw);
        }
    } else if (b == 104) {
        __shared__ float sfrf[512];
        for (int e = tid; e < 512; e += 256)
            sfrf[e] = ws[WS_FRF + e] * gf + frf[e] * (1.f - gf);
        __syncthreads();
        if (tid < 100) {
            float acc = 0.f;
            for (int c = 0; c < 512; ++c) acc += sfrf[c] * m[c * 100 + tid];
            ws[WS_FOC + tid] = fmaxf(acc, 0.f);
        }
    } else if (b < 141) {
        int o = b - 105;
        int i = o / 6, j = o % 6;
        float acc = 0.f;
        for (int k = tid; k < 12800; k += 256) {
            int c = k / 25, pq = k % 25, p = pq / 5, q = pq % 5;
            float wm = ws[WS_WRF + k] * gw + wrf[k] * (1.f - gw);
            acc += wm * m[c * 100 + (i + p) * 10 + (j + q)];
        }
        __shared__ float red[256];
        red[tid] = acc;
        __syncthreads();
        for (int s = 128; s > 0; s >>= 1) {
            if (tid < s) red[tid] += red[tid + s];
            __syncthreads();
        }
        if (tid == 0) ws[WS_WIDE + o] = fmaxf(red[0], 0.f);
    } else {
        __shared__ float smwf[100];
        __shared__ float smww[196];
        if (tid < 100) smwf[tid] = ws[WS_MWF + tid];
        if (tid < 196) smww[tid] = ws[WS_MWW + tid];
        __syncthreads();
        int t = (b - 141) * 256 + tid;   // < 51200
        int c = t / 100, hw = t % 100;
        int i = hw / 10, j = hw % 10;
        float fwf_t = ws[WS_FWF + c] * gf + fwf[c] * (1.f - gf);
        float wwacc = 0.f;
#pragma unroll
        for (int p = 0; p < 5; ++p) {
#pragma unroll
            for (int q = 0; q < 5; ++q) {
                int k = c * 25 + p * 5 + q;
                float wm = ws[WS_WWF + k] * gw + wwf[k] * (1.f - gw);
                wwacc += wm * smww[(i + p) * 14 + (j + q)];
            }
        }
        out[OUT_MT + t] = m[t] + (smwf[hw] * fwf_t + wwacc) * (1.f - erg) + 2.f * addg;
    }
}

__global__ __launch_bounds__(256) void k3_read(
    const float* __restrict__ w_cfr, const float* __restrict__ b_cfr,
    const float* __restrict__ w_cwr, const float* __restrict__ b_cwr,
    const float* __restrict__ ws, float* __restrict__ out)
{
    const int wave = (blockIdx.x * blockDim.x + threadIdx.x) >> 6;
    const int lane = threadIdx.x & 63;
    if (wave >= 2048) return;
    const float* foc = ws + WS_FOC;
    const float* wid = ws + WS_WIDE;

    float af = w_cfr[wave * 100 + lane] * foc[lane];     // lane in [0,64) < 100
    int k2 = lane + 64;
    if (k2 < 100) af += w_cfr[wave * 100 + k2] * foc[k2];
    float aw = (lane < 36) ? w_cwr[wave * 36 + lane] * wid[lane] : 0.f;
#pragma unroll
    for (int off = 32; off > 0; off >>= 1) {
        af += __shfl_down(af, off);
        aw += __shfl_down(aw, off);
    }
    if (lane == 0)
        out[wave] = (aw + b_cwr[wave]) + fmaxf(af + b_cfr[wave], 0.f);
}

extern "C" void kernel_launch(void* const* d_in, const int* in_sizes, int n_in,
                              void* d_out, int out_size, void* d_ws, size_t ws_size,
                              hipStream_t stream) {
    const float* h_t  = (const float*)d_in[0];
    const float* frf  = (const float*)d_in[1];
    const float* wrf  = (const float*)d_in[2];
    const float* fwf  = (const float*)d_in[3];
    const float* wwf  = (const float*)d_in[4];
    const float* m    = (const float*)d_in[5];
    const float* w_fg = (const float*)d_in[6];  const float* b_fg = (const float*)d_in[7];
    const float* w_wg = (const float*)d_in[8];  const float* b_wg = (const float*)d_in[9];
    const float* w_hrf= (const float*)d_in[10]; const float* b_hrf= (const float*)d_in[11];
    const float* w_hrw= (const float*)d_in[12]; const float* b_hrw= (const float*)d_in[13];
    const float* w_cfr= (const float*)d_in[14]; const float* b_cfr= (const float*)d_in[15];
    const float* w_cwr= (const float*)d_in[16]; const float* b_cwr= (const float*)d_in[17];
    const float* w_hfc= (const float*)d_in[18]; const float* b_hfc= (const float*)d_in[19];
    const float* w_hwc= (const float*)d_in[20]; const float* b_hwc= (const float*)d_in[21];
    const float* w_ag = (const float*)d_in[22]; const float* b_ag = (const float*)d_in[23];
    const float* w_eg = (const float*)d_in[24]; const float* b_eg = (const float*)d_in[25];
    const float* w_hwf= (const float*)d_in[26]; const float* b_hwf= (const float*)d_in[27];
    const float* w_hww= (const float*)d_in[28]; const float* b_hww= (const float*)d_in[29];

    float* out = (float*)d_out;
    float* ws  = (float*)d_ws;

    // K1: all h-projections, nontemporal weight stream
    {
        int blocks = (NWAVES * 64 + 255) / 256;
        hipLaunchKernelGGL(k1_gemv, dim3(blocks), dim3(256), 0, stream,
            h_t,
            w_fg, b_fg, w_wg, b_wg, w_ag, b_ag, w_eg, b_eg,
            w_hrf, b_hrf, w_hrw, b_hrw, w_hwf, b_hwf, w_hww, b_hww,
            w_hfc, b_hfc, w_hwc, b_hwc,
            ws);
    }
    // K2: gate-mix + convs + m_t
    hipLaunchKernelGGL(k2_mix_conv, dim3(341), dim3(256), 0, stream,
        frf, wrf, fwf, wwf, m, ws, out);
    // K3: read projection (one wave per row)
    hipLaunchKernelGGL(k3_read, dim3(512), dim3(256), 0, stream,
        w_cfr, b_cfr, w_cwr, b_cwr, ws, out);
}

// Round 6
// 284.576 us; speedup vs baseline: 1.0845x; 1.0003x over previous
//
#include <hip/hip_runtime.h>
#include <math.h>

#define HDIM 2048
#define NMB  512

// workspace layout (floats)
#define WS_GATES 0          // gf, gw, add, erase
#define WS_FRF   4          // 512
#define WS_WRF   516        // 12800
#define WS_FWF   13316      // 512
#define WS_WWF   13828      // 12800
#define WS_MWF   26628      // 100
#define WS_MWW   26728      // 196
#define WS_FOC   26924      // 100
#define WS_WIDE  27024      // 36

// out layout (floats)
#define OUT_READ 0          // 2048
#define OUT_FRF  2048       // 512
#define OUT_WRF  2560       // 12800
#define OUT_FWF  15360      // 512
#define OUT_WWF  15872      // 12800
#define OUT_MT   28672      // 51200

#define NROWS (4 + 512 + 12800 + 512 + 12800 + 100 + 196)  // 26924
#define NPAIRS (NROWS / 2)                                 // 13462

typedef float vfloat4 __attribute__((ext_vector_type(4)));

__global__ __launch_bounds__(256) void k1_gemv(
    const float* __restrict__ h,
    const float* __restrict__ w_fg, const float* __restrict__ b_fg,
    const float* __restrict__ w_wg, const float* __restrict__ b_wg,
    const float* __restrict__ w_ag, const float* __restrict__ b_ag,
    const float* __restrict__ w_eg, const float* __restrict__ b_eg,
    const float* __restrict__ w_hrf, const float* __restrict__ b_hrf,
    const float* __restrict__ w_hrw, const float* __restrict__ b_hrw,
    const float* __restrict__ w_hwf, const float* __restrict__ b_hwf,
    const float* __restrict__ w_hww, const float* __restrict__ b_hww,
    const float* __restrict__ w_hfc, const float* __restrict__ b_hfc,
    const float* __restrict__ w_hwc, const float* __restrict__ b_hwc,
    float* __restrict__ ws)
{
    const int lane = threadIdx.x & 63;
    const int g    = (blockIdx.x * blockDim.x + threadIdx.x) >> 6;
    if (g >= NPAIRS) return;

    // h loaded once per wave into registers (normal cached loads — L2-resident)
    const vfloat4* h4 = (const vfloat4*)h;
    vfloat4 hv[8];
#pragma unroll
    for (int s = 0; s < 8; ++s) hv[s] = h4[(s << 6) + lane];

    const int r0 = g * 2;

    const float* wp[2]; const float* bp[2];
    int bi[2], act[2], oi[2]; float* op[2];
#pragma unroll
    for (int t = 0; t < 2; ++t) {
        int r = r0 + t;
        if (r < 4) {
            if (r == 0)      { wp[t] = w_fg; bp[t] = b_fg; }
            else if (r == 1) { wp[t] = w_wg; bp[t] = b_wg; }
            else if (r == 2) { wp[t] = w_ag; bp[t] = b_ag; }
            else             { wp[t] = w_eg; bp[t] = b_eg; }
            bi[t] = 0; act[t] = (r < 2) ? 0 : 1; op[t] = ws + WS_GATES; oi[t] = r;
        } else if (r < 516) {
            int k = r - 4;      wp[t] = w_hrf + (size_t)k * HDIM; bp[t] = b_hrf; bi[t] = k; act[t] = 1; op[t] = ws + WS_FRF; oi[t] = k;
        } else if (r < 13316) {
            int k = r - 516;    wp[t] = w_hrw + (size_t)k * HDIM; bp[t] = b_hrw; bi[t] = k; act[t] = 1; op[t] = ws + WS_WRF; oi[t] = k;
        } else if (r < 13828) {
            int k = r - 13316;  wp[t] = w_hwf + (size_t)k * HDIM; bp[t] = b_hwf; bi[t] = k; act[t] = 1; op[t] = ws + WS_FWF; oi[t] = k;
        } else if (r < 26628) {
            int k = r - 13828;  wp[t] = w_hww + (size_t)k * HDIM; bp[t] = b_hww; bi[t] = k; act[t] = 1; op[t] = ws + WS_WWF; oi[t] = k;
        } else if (r < 26728) {
            int k = r - 26628;  wp[t] = w_hfc + (size_t)k * HDIM; bp[t] = b_hfc; bi[t] = k; act[t] = 2; op[t] = ws + WS_MWF; oi[t] = k;
        } else {
            int k = r - 26728;  wp[t] = w_hwc + (size_t)k * HDIM; bp[t] = b_hwc; bi[t] = k; act[t] = 2; op[t] = ws + WS_MWW; oi[t] = k;
        }
    }

    const vfloat4* wA4 = (const vfloat4*)wp[0];
    const vfloat4* wB4 = (const vfloat4*)wp[1];

    // 16 nontemporal weight loads issued back-to-back (2 rows in flight)
    vfloat4 av[8], bv[8];
#pragma unroll
    for (int s = 0; s < 8; ++s)
        av[s] = __builtin_nontemporal_load(&wA4[(s << 6) + lane]);
#pragma unroll
    for (int s = 0; s < 8; ++s)
        bv[s] = __builtin_nontemporal_load(&wB4[(s << 6) + lane]);

    float accA = 0.f, accB = 0.f;
#pragma unroll
    for (int s = 0; s < 8; ++s) {
        accA += av[s].x * hv[s].x + av[s].y * hv[s].y + av[s].z * hv[s].z + av[s].w * hv[s].w;
        accB += bv[s].x * hv[s].x + bv[s].y * hv[s].y + bv[s].z * hv[s].z + bv[s].w * hv[s].w;
    }
#pragma unroll
    for (int off = 32; off > 0; off >>= 1) {
        accA += __shfl_down(accA, off);
        accB += __shfl_down(accB, off);
    }

    if (lane == 0) {
#pragma unroll
        for (int t = 0; t < 2; ++t) {
            float x = ((t == 0) ? accA : accB) + bp[t][bi[t]];
            float y;
            if (act[t] == 0) {
                float s = 1.f / (1.f + __expf(-x));
                y = fminf(fmaxf(1.2f * s - 0.1f, 0.f), 1.f);
            } else if (act[t] == 1) {
                y = fminf(fmaxf(x, 0.f), 1.f);
            } else {
                y = fmaxf(x, 0.f);
            }
            op[t][oi[t]] = y;
        }
    }
}

// block 0..103   : elementwise gate-mix -> outputs frf_t / wrf_t / fwf_t / wwf_t
// block 104      : focused (100 outputs, reduce over 512 channels)
// block 105..140 : wide conv (36 outputs, reduce over 12800 taps)
// block 141..340 : m_t (51200 outputs, 25-tap conv each)
__global__ __launch_bounds__(256) void k2_mix_conv(
    const float* __restrict__ frf, const float* __restrict__ wrf,
    const float* __restrict__ fwf, const float* __restrict__ wwf,
    const float* __restrict__ m,
    float* __restrict__ ws, float* __restrict__ out)
{
    const float gf = ws[WS_GATES + 0];
    const float gw = ws[WS_GATES + 1];
    const float addg = ws[WS_GATES + 2];
    const float erg  = ws[WS_GATES + 3];
    const int b = blockIdx.x;
    const int tid = threadIdx.x;

    if (b < 104) {
        int e = b * 256 + tid;
        if (e < 512) {
            out[OUT_FRF + e] = ws[WS_FRF + e] * gf + frf[e] * (1.f - gf);
        } else if (e < 13312) {
            int k = e - 512;
            out[OUT_WRF + k] = ws[WS_WRF + k] * gw + wrf[k] * (1.f - gw);
        } else if (e < 13824) {
            int k = e - 13312;
            out[OUT_FWF + k] = ws[WS_FWF + k] * gf + fwf[k] * (1.f - gf);
        } else if (e < 26624) {
            int k = e - 13824;
            out[OUT_WWF + k] = ws[WS_WWF + k] * gw + wwf[k] * (1.f - gw);
        }
    } else if (b == 104) {
        __shared__ float sfrf[512];
        for (int e = tid; e < 512; e += 256)
            sfrf[e] = ws[WS_FRF + e] * gf + frf[e] * (1.f - gf);
        __syncthreads();
        if (tid < 100) {
            float acc = 0.f;
            for (int c = 0; c < 512; ++c) acc += sfrf[c] * m[c * 100 + tid];
            ws[WS_FOC + tid] = fmaxf(acc, 0.f);
        }
    } else if (b < 141) {
        int o = b - 105;
        int i = o / 6, j = o % 6;
        float acc = 0.f;
        for (int k = tid; k < 12800; k += 256) {
            int c = k / 25, pq = k % 25, p = pq / 5, q = pq % 5;
            float wm = ws[WS_WRF + k] * gw + wrf[k] * (1.f - gw);
            acc += wm * m[c * 100 + (i + p) * 10 + (j + q)];
        }
        __shared__ float red[256];
        red[tid] = acc;
        __syncthreads();
        for (int s = 128; s > 0; s >>= 1) {
            if (tid < s) red[tid] += red[tid + s];
            __syncthreads();
        }
        if (tid == 0) ws[WS_WIDE + o] = fmaxf(red[0], 0.f);
    } else {
        __shared__ float smwf[100];
        __shared__ float smww[196];
        if (tid < 100) smwf[tid] = ws[WS_MWF + tid];
        if (tid < 196) smww[tid] = ws[WS_MWW + tid];
        __syncthreads();
        int t = (b - 141) * 256 + tid;   // < 51200
        int c = t / 100, hw = t % 100;
        int i = hw / 10, j = hw % 10;
        float fwf_t = ws[WS_FWF + c] * gf + fwf[c] * (1.f - gf);
        float wwacc = 0.f;
#pragma unroll
        for (int p = 0; p < 5; ++p) {
#pragma unroll
            for (int q = 0; q < 5; ++q) {
                int k = c * 25 + p * 5 + q;
                float wm = ws[WS_WWF + k] * gw + wwf[k] * (1.f - gw);
                wwacc += wm * smww[(i + p) * 14 + (j + q)];
            }
        }
        out[OUT_MT + t] = m[t] + (smwf[hw] * fwf_t + wwacc) * (1.f - erg) + 2.f * addg;
    }
}

__global__ __launch_bounds__(256) void k3_read(
    const float* __restrict__ w_cfr, const float* __restrict__ b_cfr,
    const float* __restrict__ w_cwr, const float* __restrict__ b_cwr,
    const float* __restrict__ ws, float* __restrict__ out)
{
    const int wave = (blockIdx.x * blockDim.x + threadIdx.x) >> 6;
    const int lane = threadIdx.x & 63;
    if (wave >= 2048) return;
    const float* foc = ws + WS_FOC;
    const float* wid = ws + WS_WIDE;

    float af = w_cfr[wave * 100 + lane] * foc[lane];     // lane in [0,64) < 100
    int k2 = lane + 64;
    if (k2 < 100) af += w_cfr[wave * 100 + k2] * foc[k2];
    float aw = (lane < 36) ? w_cwr[wave * 36 + lane] * wid[lane] : 0.f;
#pragma unroll
    for (int off = 32; off > 0; off >>= 1) {
        af += __shfl_down(af, off);
        aw += __shfl_down(aw, off);
    }
    if (lane == 0)
        out[wave] = (aw + b_cwr[wave]) + fmaxf(af + b_cfr[wave], 0.f);
}

extern "C" void kernel_launch(void* const* d_in, const int* in_sizes, int n_in,
                              void* d_out, int out_size, void* d_ws, size_t ws_size,
                              hipStream_t stream) {
    const float* h_t  = (const float*)d_in[0];
    const float* frf  = (const float*)d_in[1];
    const float* wrf  = (const float*)d_in[2];
    const float* fwf  = (const float*)d_in[3];
    const float* wwf  = (const float*)d_in[4];
    const float* m    = (const float*)d_in[5];
    const float* w_fg = (const float*)d_in[6];  const float* b_fg = (const float*)d_in[7];
    const float* w_wg = (const float*)d_in[8];  const float* b_wg = (const float*)d_in[9];
    const float* w_hrf= (const float*)d_in[10]; const float* b_hrf= (const float*)d_in[11];
    const float* w_hrw= (const float*)d_in[12]; const float* b_hrw= (const float*)d_in[13];
    const float* w_cfr= (const float*)d_in[14]; const float* b_cfr= (const float*)d_in[15];
    const float* w_cwr= (const float*)d_in[16]; const float* b_cwr= (const float*)d_in[17];
    const float* w_hfc= (const float*)d_in[18]; const float* b_hfc= (const float*)d_in[19];
    const float* w_hwc= (const float*)d_in[20]; const float* b_hwc= (const float*)d_in[21];
    const float* w_ag = (const float*)d_in[22]; const float* b_ag = (const float*)d_in[23];
    const float* w_eg = (const float*)d_in[24]; const float* b_eg = (const float*)d_in[25];
    const float* w_hwf= (const float*)d_in[26]; const float* b_hwf= (const float*)d_in[27];
    const float* w_hww= (const float*)d_in[28]; const float* b_hww= (const float*)d_in[29];

    float* out = (float*)d_out;
    float* ws  = (float*)d_ws;

    // K1: all h-projections, 2 rows in flight per wave, nontemporal weight stream
    {
        int blocks = (NPAIRS + 3) / 4;   // 4 waves per 256-thread block
        hipLaunchKernelGGL(k1_gemv, dim3(blocks), dim3(256), 0, stream,
            h_t,
            w_fg, b_fg, w_wg, b_wg, w_ag, b_ag, w_eg, b_eg,
            w_hrf, b_hrf, w_hrw, b_hrw, w_hwf, b_hwf, w_hww, b_hww,
            w_hfc, b_hfc, w_hwc, b_hwc,
            ws);
    }
    // K2: gate-mix + convs + m_t
    hipLaunchKernelGGL(k2_mix_conv, dim3(341), dim3(256), 0, stream,
        frf, wrf, fwf, wwf, m, ws, out);
    // K3: read projection (one wave per row)
    hipLaunchKernelGGL(k3_read, dim3(512), dim3(256), 0, stream,
        w_cfr, b_cfr, w_cwr, b_cwr, ws, out);
}